// Round 8
// baseline (92237.805 us; speedup 1.0000x reference)
//
#include <hip/hip_runtime.h>
#include <hip/hip_bf16.h>

// Problem constants
#define HH 1024
#define BB 128
#define TT 512
#define NWG 32       // 4 row-groups (mg) x 8 N-slices (ng); XCD = blockIdx%8 = ng
#define NTH 512      // 8 waves: 2(M) x 4(N), wave tile 16 x 32, full K per wave
#define NGRP 8       // WGs per group

typedef float        f32x4 __attribute__((ext_vector_type(4)));
typedef short        s16x8 __attribute__((ext_vector_type(8)));

__device__ __forceinline__ unsigned short bf16b(float f) {
    union { __hip_bfloat16 h; unsigned short u; } cv;
    cv.h = __float2bfloat16(f);
    return cv.u;
}

__device__ __forceinline__ float gelu_exact(float x) {
    return 0.5f * x * (1.0f + erff(x * 0.70710678118654752440f));
}

// --- device-coherent (L1+L2-bypass) accesses for cross-WG data.
__device__ __forceinline__ void sc_load_b16x8(s16x8& v, const unsigned short* p) {
    asm volatile("global_load_dwordx4 %0, %1, off sc0 sc1" : "=v"(v) : "v"(p));
}
__device__ __forceinline__ void sc_load_u32(unsigned& v, const unsigned* p) {
    asm volatile("global_load_dword %0, %1, off sc0 sc1" : "=v"(v) : "v"(p));
}
__device__ __forceinline__ void sc_store_b16(unsigned short* p, unsigned int v) {
    asm volatile("global_store_short %0, %1, off sc0 sc1" :: "v"(p), "v"(v) : "memory");
}
__device__ __forceinline__ void sc_store_u32(unsigned* p, unsigned int v) {
    asm volatile("global_store_dword %0, %1, off sc0 sc1" :: "v"(p), "v"(v) : "memory");
}
// --- plain cached load inside the hand-counted asm stream (weights -> L2 hit).
__device__ __forceinline__ void pl_load_b16x8(s16x8& v, const unsigned short* p) {
    asm volatile("global_load_dwordx4 %0, %1, off" : "=v"(v) : "v"(p));
}
// --- non-temporal store for streaming Out writes (no L2 pollution).
__device__ __forceinline__ void nt_store_f32(float* p, float v) {
    asm volatile("global_store_dword %0, %1, off nt" :: "v"(p), "v"(v) : "memory");
}

// ---------------------------------------------------------------------------
// Pack fp32 weight W[K][N] (row-major) into MFMA B-fragment layout, bf16:
//   P[((ntile*KT + ktile)*64 + lane)*8 + j] =
//       bf16(W[ktile*32 + (lane>>4)*8 + j][ntile*16 + (lane&15)])
// ---------------------------------------------------------------------------
__global__ __launch_bounds__(256) void pack_w_kernel(const float* __restrict__ W,
                                                     unsigned short* __restrict__ P,
                                                     int K, int N) {
    int tid = blockIdx.x * 256 + threadIdx.x;
    int KT = K >> 5;
    int total = (N >> 4) * KT * 64;
    if (tid >= total) return;
    int lane  = tid & 63;
    int ktile = (tid >> 6) % KT;
    int ntile = (tid >> 6) / KT;
    int k0 = ktile * 32 + (lane >> 4) * 8;
    int n  = ntile * 16 + (lane & 15);
    unsigned short tmp[8];
#pragma unroll
    for (int j = 0; j < 8; ++j)
        tmp[j] = bf16b(W[(size_t)(k0 + j) * N + n]);
    *reinterpret_cast<s16x8*>(P + (size_t)tid * 8) = *reinterpret_cast<const s16x8*>(tmp);
}

// ---------------------------------------------------------------------------
// Per-GROUP barrier among 8 WGs. One slot per 64B line (16 u32 stride) so
// arrive-stores and polls never collide on a line. Wave 0 polls (lane&7 ->
// slot), with s_sleep backoff after the first miss (round-6/7 lesson: unthrottled
// polling saturates the coherent fabric and inflates its own latency).
// ---------------------------------------------------------------------------
__device__ __forceinline__ void gbar_arrive(unsigned* gs, int ng, unsigned rnd) {
    asm volatile("s_waitcnt vmcnt(0)" ::: "memory");  // drain my sc/nt stores
    __syncthreads();                                   // all 8 waves drained
    if (threadIdx.x == 0)
        sc_store_u32(gs + ng * 16, rnd);
}
__device__ __forceinline__ void gbar_wait(const unsigned* gs, unsigned rnd) {
    if (rnd != 0 && threadIdx.x < 64) {
        const unsigned* p = gs + (threadIdx.x & 7) * 16;
        for (;;) {
            unsigned v;
            sc_load_u32(v, p);
            asm volatile("s_waitcnt vmcnt(0)" ::: "memory");
            if (__all(v >= rnd)) break;
            __builtin_amdgcn_s_sleep(2);   // ~128 clk backoff: caps poll rate
        }
    }
    __syncthreads();
    __builtin_amdgcn_sched_barrier(0);
}

// ---------------------------------------------------------------------------
// 2-deep software-pipelined K-loop, dual N-fragment. A via sc loads
// (activations, coherent), B via plain loads (weights, L2-resident).
// Batch = 4 kt = 4 A + 8 B = 12 loads; counted vmcnt(12) keeps the next batch
// in flight across each MFMA cluster; only the last batch drains to 0.
// ---------------------------------------------------------------------------
template <int NB>
__device__ __forceinline__ void kloop_pipe2(const unsigned short* Abase,
                                            const unsigned short* bp0,
                                            const unsigned short* bp1,
                                            f32x4& acc0, f32x4& acc1) {
    s16x8 a[2][4], b0[2][4], b1[2][4];
#pragma unroll
    for (int j = 0; j < 4; ++j) sc_load_b16x8(a[0][j], Abase + (size_t)j * 32);
#pragma unroll
    for (int j = 0; j < 4; ++j) pl_load_b16x8(b0[0][j], bp0 + (size_t)j * 512);
#pragma unroll
    for (int j = 0; j < 4; ++j) pl_load_b16x8(b1[0][j], bp1 + (size_t)j * 512);
#pragma unroll
    for (int blk = 0; blk < NB; ++blk) {
        const int cur = blk & 1, nxt = cur ^ 1;
        if (blk + 1 < NB) {
            const int kb = (blk + 1) * 4;
#pragma unroll
            for (int j = 0; j < 4; ++j)
                sc_load_b16x8(a[nxt][j], Abase + (size_t)(kb + j) * 32);
#pragma unroll
            for (int j = 0; j < 4; ++j)
                pl_load_b16x8(b0[nxt][j], bp0 + (size_t)(kb + j) * 512);
#pragma unroll
            for (int j = 0; j < 4; ++j)
                pl_load_b16x8(b1[nxt][j], bp1 + (size_t)(kb + j) * 512);
            asm volatile("s_waitcnt vmcnt(12)" ::: "memory");
        } else {
            asm volatile("s_waitcnt vmcnt(0)" ::: "memory");
        }
        __builtin_amdgcn_sched_barrier(0);
#pragma unroll
        for (int j = 0; j < 4; ++j) {
            acc0 = __builtin_amdgcn_mfma_f32_16x16x32_bf16(a[cur][j], b0[cur][j], acc0, 0, 0, 0);
            acc1 = __builtin_amdgcn_mfma_f32_16x16x32_bf16(a[cur][j], b1[cur][j], acc1, 0, 0, 0);
        }
    }
}

// K-loop over the fp32 input frame, dual N-fragment: plain cached loads,
// pure C++ (compiler pipelines). Depends only on static X -> callers run it
// BEFORE the barrier wait to hide barrier latency.
__device__ __forceinline__ void kloop_x2(const float* xt,
                                         const unsigned short* bp0,
                                         const unsigned short* bp1,
                                         f32x4& acc0, f32x4& acc1) {
#pragma unroll 4
    for (int kt = 0; kt < 32; ++kt) {
        f32x4 lo = *reinterpret_cast<const f32x4*>(xt + kt * 32);
        f32x4 hi = *reinterpret_cast<const f32x4*>(xt + kt * 32 + 4);
        s16x8 a;
#pragma unroll
        for (int j = 0; j < 4; ++j) {
            a[j]     = (short)bf16b(lo[j]);
            a[j + 4] = (short)bf16b(hi[j]);
        }
        s16x8 b0 = *reinterpret_cast<const s16x8*>(bp0 + (size_t)kt * 512);
        s16x8 b1 = *reinterpret_cast<const s16x8*>(bp1 + (size_t)kt * 512);
        acc0 = __builtin_amdgcn_mfma_f32_16x16x32_bf16(a, b0, acc0, 0, 0, 0);
        acc1 = __builtin_amdgcn_mfma_f32_16x16x32_bf16(a, b1, acc1, 0, 0, 0);
    }
}

// ---------------------------------------------------------------------------
// Persistent kernel. 4 independent row-groups (mg = wg>>3, 32 rows each),
// each synced among its own 8 WGs (ng = wg&7 -> 128-col slice).
//   blockIdx = mg*8+ng -> XCD = ng: each XCD hosts ONE 128-col weight slice
//   (~1.5 MB packed, L2-resident) shared by its 4 resident WGs.
// 8 waves: wm = w>>2 (2 M-tiles of 16), wn = w&3 (4 N-tiles of 32).
// Each wave owns its 16x32 output for the FULL K -> no cross-wave reduction.
// Weights/biases/X: plain cached. Activations/state: sc0sc1. Out: nt.
// ---------------------------------------------------------------------------
__global__ __launch_bounds__(512, 1) void persist_kernel(
    const float* __restrict__ X,
    const unsigned short* __restrict__ p_a1, const float* __restrict__ ab1,
    const unsigned short* __restrict__ p_a2, const float* __restrict__ ab2,
    const unsigned short* __restrict__ p_g1, const float* __restrict__ gb1,
    const unsigned short* __restrict__ p_g2, const float* __restrict__ gb2,
    float* __restrict__ Out,
    unsigned short* state, unsigned short* h1, unsigned short* albf,
    unsigned short* h2,
    unsigned* slots)
{
    const int wg   = blockIdx.x;
    const int ng   = wg & (NGRP - 1);
    const int mg   = wg >> 3;
    const int tid  = threadIdx.x;
    const int lane = tid & 63;
    const int w    = tid >> 6;        // 0..7
    const int wm   = w >> 2;          // 0..1
    const int wn   = w & 3;           // 0..3
    const int r    = lane & 15;
    const int q    = lane >> 4;

    const int mrow = mg * 32 + wm * 16;          // wave M base
    const int ncol = ng * 128 + wn * 32;         // wave N base (2 frags: +0,+16)
    const int nt0  = ncol >> 4;                  // first B-fragment n-tile

    unsigned* gs = slots + mg * (NGRP * 16);     // this group's 8 spread slots

    const size_t arow_off = (size_t)(mrow + r) * HH + q * 8;
    const float* xrow = X + (size_t)(mrow + r) * (TT * HH) + q * 8;

    // B-fragment bases: frag(ntile,kt) at ((ntile*KT + kt)*64 + lane)*8.
    // K=2048 (KT=64): ntile stride 64*512; K=1024 (KT=32): 32*512. kt stride 512.
    const unsigned short* a1_0 = p_a1 + ((size_t)nt0       * 64) * 512 + (size_t)lane * 8;
    const unsigned short* a1_1 = p_a1 + ((size_t)(nt0 + 1) * 64) * 512 + (size_t)lane * 8;
    const unsigned short* g1_0 = p_g1 + ((size_t)nt0       * 64) * 512 + (size_t)lane * 8;
    const unsigned short* g1_1 = p_g1 + ((size_t)(nt0 + 1) * 64) * 512 + (size_t)lane * 8;
    const unsigned short* a2_0 = p_a2 + ((size_t)nt0       * 32) * 512 + (size_t)lane * 8;
    const unsigned short* a2_1 = p_a2 + ((size_t)(nt0 + 1) * 32) * 512 + (size_t)lane * 8;
    const unsigned short* g2_0 = p_g2 + ((size_t)nt0       * 32) * 512 + (size_t)lane * 8;
    const unsigned short* g2_1 = p_g2 + ((size_t)(nt0 + 1) * 32) * 512 + (size_t)lane * 8;

    const int c0 = ncol + r, c1 = ncol + 16 + r;
    const float bA1_0 = ab1[c0], bA1_1 = ab1[c1];
    const float bA2_0 = ab2[c0], bA2_1 = ab2[c1];
    const float bG1_0 = gb1[c0], bG1_1 = gb1[c1];
    const float bG2_0 = gb2[c0], bG2_1 = gb2[c1];

    float al0[4], al1[4];   // fp32 'aligned' tile, reused in G4 blend

    for (int t = 0; t < TT; ++t) {
        const float* xt = xrow + (size_t)t * HH;
        const unsigned rb = 4u * (unsigned)t;

        // ------- G1: h1 = gelu(concat(x_t, state) @ aw1 + ab1), K=2048 -----
        {
            f32x4 acc0 = {}, acc1 = {};
            kloop_x2(xt, a1_0, a1_1, acc0, acc1);          // x half BEFORE wait
            gbar_wait(gs, rb);                             // state ready (G4 t-1)
            kloop_pipe2<8>(state + arow_off,
                           a1_0 + (size_t)32 * 512, a1_1 + (size_t)32 * 512,
                           acc0, acc1);
#pragma unroll
            for (int j = 0; j < 4; ++j) {
                size_t rowo = (size_t)(mrow + q * 4 + j) * HH;
                sc_store_b16(h1 + rowo + c0, bf16b(gelu_exact(acc0[j] + bA1_0)));
                sc_store_b16(h1 + rowo + c1, bf16b(gelu_exact(acc1[j] + bA1_1)));
            }
        }
        gbar_arrive(gs, ng, rb + 1);

        // ------- G2: aligned = h1 @ aw2 + ab2, K=1024 ----------------------
        {
            gbar_wait(gs, rb + 1);
            f32x4 acc0 = {}, acc1 = {};
            kloop_pipe2<8>(h1 + arow_off, a2_0, a2_1, acc0, acc1);
#pragma unroll
            for (int j = 0; j < 4; ++j) {
                size_t rowo = (size_t)(mrow + q * 4 + j) * HH;
                float v0 = acc0[j] + bA2_0, v1 = acc1[j] + bA2_1;
                al0[j] = v0; al1[j] = v1;
                sc_store_b16(albf + rowo + c0, bf16b(v0));
                sc_store_b16(albf + rowo + c1, bf16b(v1));
            }
        }
        gbar_arrive(gs, ng, rb + 2);

        // ------- G3: h2 = gelu(concat(x_t, aligned) @ gw1 + gb1), K=2048 ---
        {
            f32x4 acc0 = {}, acc1 = {};
            kloop_x2(xt, g1_0, g1_1, acc0, acc1);          // x half BEFORE wait
            gbar_wait(gs, rb + 2);                         // albf ready
            kloop_pipe2<8>(albf + arow_off,
                           g1_0 + (size_t)32 * 512, g1_1 + (size_t)32 * 512,
                           acc0, acc1);
#pragma unroll
            for (int j = 0; j < 4; ++j) {
                size_t rowo = (size_t)(mrow + q * 4 + j) * HH;
                sc_store_b16(h2 + rowo + c0, bf16b(gelu_exact(acc0[j] + bG1_0)));
                sc_store_b16(h2 + rowo + c1, bf16b(gelu_exact(acc1[j] + bG1_1)));
            }
        }
        gbar_arrive(gs, ng, rb + 3);

        // ------- G4: gate = sigmoid(h2 @ gw2 + gb2); blend; next state -----
        {
            gbar_wait(gs, rb + 3);
            f32x4 acc0 = {}, acc1 = {};
            kloop_pipe2<8>(h2 + arow_off, g2_0, g2_1, acc0, acc1);
#pragma unroll
            for (int j = 0; j < 4; ++j) {
                int row = mrow + q * 4 + j;
                size_t xo = (size_t)row * (TT * HH) + (size_t)t * HH;
                size_t so = (size_t)row * HH;
                float g0 = 1.0f / (1.0f + expf(-(acc0[j] + bG2_0)));
                float g1 = 1.0f / (1.0f + expf(-(acc1[j] + bG2_1)));
                float o0 = g0 * al0[j] + (1.0f - g0) * X[xo + c0];
                float o1 = g1 * al1[j] + (1.0f - g1) * X[xo + c1];
                nt_store_f32(Out + xo + c0, o0);
                nt_store_f32(Out + xo + c1, o1);
                sc_store_b16(state + so + c0, bf16b(o0));
                sc_store_b16(state + so + c1, bf16b(o1));
            }
        }
        gbar_arrive(gs, ng, rb + 4);
    }
}

extern "C" void kernel_launch(void* const* d_in, const int* in_sizes, int n_in,
                              void* d_out, int out_size, void* d_ws, size_t ws_size,
                              hipStream_t stream) {
    (void)in_sizes; (void)n_in; (void)out_size; (void)ws_size;
    const float* X   = (const float*)d_in[0];
    const float* aw1 = (const float*)d_in[1];
    const float* ab1 = (const float*)d_in[2];
    const float* aw2 = (const float*)d_in[3];
    const float* ab2 = (const float*)d_in[4];
    const float* gw1 = (const float*)d_in[5];
    const float* gb1 = (const float*)d_in[6];
    const float* gw2 = (const float*)d_in[7];
    const float* gb2 = (const float*)d_in[8];
    float* Out = (float*)d_out;

    char* ws = (char*)d_ws;
    unsigned short* p_a1 = (unsigned short*)(ws);                 // 4 MB
    unsigned short* p_g1 = (unsigned short*)(ws + (4u  << 20));   // 4 MB
    unsigned short* p_a2 = (unsigned short*)(ws + (8u  << 20));   // 2 MB
    unsigned short* p_g2 = (unsigned short*)(ws + (10u << 20));   // 2 MB
    char* ctrl = ws + (12u << 20);
    unsigned* slots = (unsigned*)ctrl;                            // 4 grp x 8 slot x 64B
    unsigned short* state = (unsigned short*)(ctrl + 4096);       // 256 KB
    unsigned short* h1    = state + (size_t)BB * HH;              // 256 KB
    unsigned short* albf  = h1    + (size_t)BB * HH;              // 256 KB
    unsigned short* h2    = albf  + (size_t)BB * HH;              // 256 KB

    pack_w_kernel<<<(64 * 64 * 64 + 255) / 256, 256, 0, stream>>>(aw1, p_a1, 2048, 1024);
    pack_w_kernel<<<(64 * 64 * 64 + 255) / 256, 256, 0, stream>>>(gw1, p_g1, 2048, 1024);
    pack_w_kernel<<<(64 * 32 * 64 + 255) / 256, 256, 0, stream>>>(aw2, p_a2, 1024, 1024);
    pack_w_kernel<<<(64 * 32 * 64 + 255) / 256, 256, 0, stream>>>(gw2, p_g2, 1024, 1024);
    // Zero barrier slots + recurrent state every call (graph-replay safe).
    hipMemsetAsync(ctrl, 0, 4096 + (size_t)BB * HH * sizeof(unsigned short), stream);

    persist_kernel<<<NWG, NTH, 0, stream>>>(X, p_a1, ab1, p_a2, ab2,
                                            p_g1, gb1, p_g2, gb2,
                                            Out, state, h1, albf, h2,
                                            slots);
}

// Round 9
// 75498.059 us; speedup vs baseline: 1.2217x; 1.2217x over previous
//
#include <hip/hip_runtime.h>
#include <hip/hip_bf16.h>

// Problem constants
#define HH 1024
#define BB 128
#define TT 512
#define NWG 32       // 4 row-groups (mg) x 8 N-slices (ng); XCD = blockIdx%8 = ng
#define NTH 1024     // 16 waves: 2(M) x 8(N), wave tile 16x16, full K per wave
#define NGRP 8       // WGs per group

typedef float        f32x4 __attribute__((ext_vector_type(4)));
typedef short        s16x8 __attribute__((ext_vector_type(8)));

__device__ __forceinline__ unsigned short bf16b(float f) {
    union { __hip_bfloat16 h; unsigned short u; } cv;
    cv.h = __float2bfloat16(f);
    return cv.u;
}

__device__ __forceinline__ float gelu_exact(float x) {
    return 0.5f * x * (1.0f + erff(x * 0.70710678118654752440f));
}

// --- device-coherent (system-scope, L1+L2-bypass) accesses for cross-WG data.
__device__ __forceinline__ void sc_load_b16x8(s16x8& v, const unsigned short* p) {
    asm volatile("global_load_dwordx4 %0, %1, off sc0 sc1" : "=v"(v) : "v"(p));
}
__device__ __forceinline__ void sc_load_u32(unsigned& v, const unsigned* p) {
    asm volatile("global_load_dword %0, %1, off sc0 sc1" : "=v"(v) : "v"(p));
}
__device__ __forceinline__ void sc_store_b16(unsigned short* p, unsigned int v) {
    asm volatile("global_store_short %0, %1, off sc0 sc1" :: "v"(p), "v"(v) : "memory");
}
__device__ __forceinline__ void sc_store_u32(unsigned* p, unsigned int v) {
    asm volatile("global_store_dword %0, %1, off sc0 sc1" :: "v"(p), "v"(v) : "memory");
}
// --- plain cached load inside the hand-counted asm stream (weights -> L2 hit).
__device__ __forceinline__ void pl_load_b16x8(s16x8& v, const unsigned short* p) {
    asm volatile("global_load_dwordx4 %0, %1, off" : "=v"(v) : "v"(p));
}
// --- non-temporal store for streaming Out writes (no L2/MALL allocate).
__device__ __forceinline__ void nt_store_f32(float* p, float v) {
    asm volatile("global_store_dword %0, %1, off nt" :: "v"(p), "v"(v) : "memory");
}
__device__ __forceinline__ void vm_wait0() {
    asm volatile("s_waitcnt vmcnt(0)" ::: "memory");
    __builtin_amdgcn_sched_barrier(0);   // rule #18
}

// ---------------------------------------------------------------------------
// Pack fp32 weight W[K][N] (row-major) into MFMA B-fragment layout, bf16:
//   P[((ntile*KT + ktile)*64 + lane)*8 + j] =
//       bf16(W[ktile*32 + (lane>>4)*8 + j][ntile*16 + (lane&15)])
// ---------------------------------------------------------------------------
__global__ __launch_bounds__(256) void pack_w_kernel(const float* __restrict__ W,
                                                     unsigned short* __restrict__ P,
                                                     int K, int N) {
    int tid = blockIdx.x * 256 + threadIdx.x;
    int KT = K >> 5;
    int total = (N >> 4) * KT * 64;
    if (tid >= total) return;
    int lane  = tid & 63;
    int ktile = (tid >> 6) % KT;
    int ntile = (tid >> 6) / KT;
    int k0 = ktile * 32 + (lane >> 4) * 8;
    int n  = ntile * 16 + (lane & 15);
    unsigned short tmp[8];
#pragma unroll
    for (int j = 0; j < 8; ++j)
        tmp[j] = bf16b(W[(size_t)(k0 + j) * N + n]);
    *reinterpret_cast<s16x8*>(P + (size_t)tid * 8) = *reinterpret_cast<const s16x8*>(tmp);
}

// ---------------------------------------------------------------------------
// Per-GROUP barrier among 8 WGs. One slot per 64B line; wave 0 polls with
// s_sleep backoff (r6/r7 lesson: unthrottled wide polling floods the fabric).
// ---------------------------------------------------------------------------
__device__ __forceinline__ void gbar_arrive(unsigned* gs, int ng, unsigned rnd) {
    asm volatile("s_waitcnt vmcnt(0)" ::: "memory");  // drain my sc/nt stores
    __syncthreads();                                   // all 16 waves drained
    if (threadIdx.x == 0)
        sc_store_u32(gs + ng * 16, rnd);
}
__device__ __forceinline__ void gbar_wait(const unsigned* gs, unsigned rnd) {
    if (rnd != 0 && threadIdx.x < 64) {
        const unsigned* p = gs + (threadIdx.x & 7) * 16;
        for (;;) {
            unsigned v;
            sc_load_u32(v, p);
            asm volatile("s_waitcnt vmcnt(0)" ::: "memory");
            if (__all(v >= rnd)) break;
            __builtin_amdgcn_s_sleep(1);
        }
    }
    __syncthreads();
    __builtin_amdgcn_sched_barrier(0);
}

// ---------------------------------------------------------------------------
// Burst-stage a 32x1024 bf16 activation slab (64 KB) into LDS.
// Global: row-major, perfectly coalesced (1024 thr x 16 B x 4 iters, ALL in
// flight at once -> ~64 outstanding loads/wave covers MALL latency).
// LDS layout: byte = row*2048 + ((c8*16) ^ ((row&7)<<4))  [c8 = col/8]
//   - write: contiguous-permuted within 128B blocks -> even bank spread
//   - read (frag): lanes (r,q) -> 8 slots x 8 lanes -> even 8x over 32 banks
// ---------------------------------------------------------------------------
__device__ __forceinline__ void stage_slab(char* lds, const unsigned short* slab,
                                           int tid) {
    s16x8 v[4];
#pragma unroll
    for (int i = 0; i < 4; ++i) {
        int lin = i * 1024 + tid;
        sc_load_b16x8(v[i], slab + (size_t)lin * 8);
    }
    vm_wait0();
#pragma unroll
    for (int i = 0; i < 4; ++i) {
        int lin = i * 1024 + tid;
        int row = lin >> 7, c8 = lin & 127;
        *reinterpret_cast<s16x8*>(lds + row * 2048 + ((c8 * 16) ^ ((row & 7) << 4))) = v[i];
    }
}

// ---------------------------------------------------------------------------
// K-loop: A-fragments from staged LDS, B (weights) from L2 via counted-vmcnt
// 2-deep pipeline (8 kt per batch). lgkmcnt for ds_read auto-inserted.
// ---------------------------------------------------------------------------
__device__ __forceinline__ f32x4 kloop_staged(const char* lds, int row_l, int q,
                                              const unsigned short* bp) {
    const int xr = (row_l & 7) << 4;
    const char* lbase = lds + row_l * 2048;
    f32x4 acc = {};
    s16x8 b[2][8];
#pragma unroll
    for (int j = 0; j < 8; ++j) pl_load_b16x8(b[0][j], bp + (size_t)j * 512);
#pragma unroll
    for (int blk = 0; blk < 4; ++blk) {
        const int cur = blk & 1, nxt = cur ^ 1;
        if (blk < 3) {
#pragma unroll
            for (int j = 0; j < 8; ++j)
                pl_load_b16x8(b[nxt][j], bp + (size_t)((blk + 1) * 8 + j) * 512);
            asm volatile("s_waitcnt vmcnt(8)" ::: "memory");
        } else {
            asm volatile("s_waitcnt vmcnt(0)" ::: "memory");
        }
        __builtin_amdgcn_sched_barrier(0);
#pragma unroll
        for (int j = 0; j < 8; ++j) {
            int kt = blk * 8 + j;
            s16x8 a = *reinterpret_cast<const s16x8*>(lbase + ((kt * 64 + q * 16) ^ xr));
            acc = __builtin_amdgcn_mfma_f32_16x16x32_bf16(a, b[cur][j], acc, 0, 0, 0);
        }
    }
    return acc;
}

// K-loop over the fp32 input frame: plain cached loads, pure C++ (compiler
// pipelines). Depends only on static X -> run BEFORE the barrier wait.
__device__ __forceinline__ f32x4 kloop_x(const float* xt, const unsigned short* bp) {
    f32x4 acc = {};
#pragma unroll 4
    for (int kt = 0; kt < 32; ++kt) {
        f32x4 lo = *reinterpret_cast<const f32x4*>(xt + kt * 32);
        f32x4 hi = *reinterpret_cast<const f32x4*>(xt + kt * 32 + 4);
        s16x8 a;
#pragma unroll
        for (int j = 0; j < 4; ++j) {
            a[j]     = (short)bf16b(lo[j]);
            a[j + 4] = (short)bf16b(hi[j]);
        }
        s16x8 b = *reinterpret_cast<const s16x8*>(bp + (size_t)kt * 512);
        acc = __builtin_amdgcn_mfma_f32_16x16x32_bf16(a, b, acc, 0, 0, 0);
    }
    return acc;
}

// ---------------------------------------------------------------------------
// Persistent kernel. 4 independent row-groups (mg = wg>>3, 32 rows each),
// each synced among its own 8 WGs (ng = wg&7 -> 128-col slice).
//   blockIdx%8 = ng -> XCD: each XCD hosts ONE 128-col weight slice
//   (~1.5 MB packed, L2-resident) shared by its 4 resident WGs.
// 16 waves: wm = w>>3 (2 M-tiles of 16), wn = w&7 (8 N-tiles of 16).
// Each wave owns a 16x16 output tile for the FULL K -> no reduction.
// Weights/biases/X: plain cached. Activations: sc via LDS stage. Out: nt.
// ---------------------------------------------------------------------------
__global__ __launch_bounds__(1024, 1) void persist_kernel(
    const float* __restrict__ X,
    const unsigned short* __restrict__ p_a1, const float* __restrict__ ab1,
    const unsigned short* __restrict__ p_a2, const float* __restrict__ ab2,
    const unsigned short* __restrict__ p_g1, const float* __restrict__ gb1,
    const unsigned short* __restrict__ p_g2, const float* __restrict__ gb2,
    float* __restrict__ Out,
    unsigned short* state, unsigned short* h1, unsigned short* albf,
    unsigned short* h2,
    unsigned* slots)
{
    __shared__ __align__(16) char ldsb[65536];   // 64 KB staged A-slab

    const int wg   = blockIdx.x;
    const int ng   = wg & (NGRP - 1);
    const int mg   = wg >> 3;
    const int tid  = threadIdx.x;
    const int lane = tid & 63;
    const int w    = tid >> 6;        // 0..15
    const int wm   = w >> 3;          // 0..1
    const int wn   = w & 7;           // 0..7
    const int r    = lane & 15;
    const int q    = lane >> 4;

    const int mrow  = mg * 32 + wm * 16;         // wave M base (global)
    const int row_l = wm * 16 + r;               // slab-local A row
    const int ncol  = ng * 128 + wn * 16;        // wave N base
    const int ntile = ncol >> 4;

    unsigned* gs = slots + mg * (NGRP * 16);     // this group's 8 spread slots

    const size_t slab_off = (size_t)mg * 32 * HH;  // group's row-slab offset
    const float* xrow = X + (size_t)(mrow + r) * (TT * HH) + q * 8;

    // B-fragment bases: frag(ntile,kt) at ((ntile*KT + kt)*64 + lane)*8.
    const unsigned short* a1 = p_a1 + ((size_t)ntile * 64) * 512 + (size_t)lane * 8;
    const unsigned short* g1 = p_g1 + ((size_t)ntile * 64) * 512 + (size_t)lane * 8;
    const unsigned short* a2 = p_a2 + ((size_t)ntile * 32) * 512 + (size_t)lane * 8;
    const unsigned short* g2 = p_g2 + ((size_t)ntile * 32) * 512 + (size_t)lane * 8;

    const int c0 = ncol + r;
    const float bA1 = ab1[c0], bA2 = ab2[c0], bG1 = gb1[c0], bG2 = gb2[c0];

    float al_reg[4];   // fp32 'aligned' tile, carried G2 -> G4 in registers

    for (int t = 0; t < TT; ++t) {
        const float* xt = xrow + (size_t)t * HH;
        const unsigned rb = 4u * (unsigned)t;

        // ------- G1: h1 = gelu(concat(x_t, state) @ aw1 + ab1), K=2048 -----
        {
            f32x4 acc = kloop_x(xt, a1);                  // x half BEFORE wait
            gbar_wait(gs, rb);                            // state ready (G4 t-1)
            stage_slab(ldsb, state + slab_off, tid);
            __syncthreads();
            acc += kloop_staged(ldsb, row_l, q, a1 + (size_t)32 * 512);
#pragma unroll
            for (int j = 0; j < 4; ++j) {
                size_t rowo = (size_t)(mrow + q * 4 + j) * HH;
                sc_store_b16(h1 + rowo + c0, bf16b(gelu_exact(acc[j] + bA1)));
            }
        }
        gbar_arrive(gs, ng, rb + 1);

        // ------- G2: aligned = h1 @ aw2 + ab2, K=1024 ----------------------
        {
            gbar_wait(gs, rb + 1);
            stage_slab(ldsb, h1 + slab_off, tid);
            __syncthreads();
            f32x4 acc = kloop_staged(ldsb, row_l, q, a2);
#pragma unroll
            for (int j = 0; j < 4; ++j) {
                size_t rowo = (size_t)(mrow + q * 4 + j) * HH;
                float v = acc[j] + bA2;
                al_reg[j] = v;
                sc_store_b16(albf + rowo + c0, bf16b(v));
            }
        }
        gbar_arrive(gs, ng, rb + 2);

        // ------- G3: h2 = gelu(concat(x_t, aligned) @ gw1 + gb1), K=2048 ---
        {
            f32x4 acc = kloop_x(xt, g1);                  // x half BEFORE wait
            gbar_wait(gs, rb + 2);                        // albf ready
            stage_slab(ldsb, albf + slab_off, tid);
            __syncthreads();
            acc += kloop_staged(ldsb, row_l, q, g1 + (size_t)32 * 512);
#pragma unroll
            for (int j = 0; j < 4; ++j) {
                size_t rowo = (size_t)(mrow + q * 4 + j) * HH;
                sc_store_b16(h2 + rowo + c0, bf16b(gelu_exact(acc[j] + bG1)));
            }
        }
        gbar_arrive(gs, ng, rb + 3);

        // ------- G4: gate = sigmoid(h2 @ gw2 + gb2); blend; next state -----
        {
            gbar_wait(gs, rb + 3);
            stage_slab(ldsb, h2 + slab_off, tid);
            __syncthreads();
            f32x4 acc = kloop_staged(ldsb, row_l, q, g2);
#pragma unroll
            for (int j = 0; j < 4; ++j) {
                int row = mrow + q * 4 + j;
                size_t xo = (size_t)row * (TT * HH) + (size_t)t * HH;
                float g  = 1.0f / (1.0f + expf(-(acc[j] + bG2)));
                float o  = g * al_reg[j] + (1.0f - g) * X[xo + c0];
                nt_store_f32(Out + xo + c0, o);
                sc_store_b16(state + (size_t)row * HH + c0, bf16b(o));
            }
        }
        gbar_arrive(gs, ng, rb + 4);
    }
}

extern "C" void kernel_launch(void* const* d_in, const int* in_sizes, int n_in,
                              void* d_out, int out_size, void* d_ws, size_t ws_size,
                              hipStream_t stream) {
    (void)in_sizes; (void)n_in; (void)out_size; (void)ws_size;
    const float* X   = (const float*)d_in[0];
    const float* aw1 = (const float*)d_in[1];
    const float* ab1 = (const float*)d_in[2];
    const float* aw2 = (const float*)d_in[3];
    const float* ab2 = (const float*)d_in[4];
    const float* gw1 = (const float*)d_in[5];
    const float* gb1 = (const float*)d_in[6];
    const float* gw2 = (const float*)d_in[7];
    const float* gb2 = (const float*)d_in[8];
    float* Out = (float*)d_out;

    char* ws = (char*)d_ws;
    unsigned short* p_a1 = (unsigned short*)(ws);                 // 4 MB
    unsigned short* p_g1 = (unsigned short*)(ws + (4u  << 20));   // 4 MB
    unsigned short* p_a2 = (unsigned short*)(ws + (8u  << 20));   // 2 MB
    unsigned short* p_g2 = (unsigned short*)(ws + (10u << 20));   // 2 MB
    char* ctrl = ws + (12u << 20);
    unsigned* slots = (unsigned*)ctrl;                            // 4 grp x 8 slot x 64B
    unsigned short* state = (unsigned short*)(ctrl + 4096);       // 256 KB
    unsigned short* h1    = state + (size_t)BB * HH;              // 256 KB
    unsigned short* albf  = h1    + (size_t)BB * HH;              // 256 KB
    unsigned short* h2    = albf  + (size_t)BB * HH;              // 256 KB

    pack_w_kernel<<<(64 * 64 * 64 + 255) / 256, 256, 0, stream>>>(aw1, p_a1, 2048, 1024);
    pack_w_kernel<<<(64 * 64 * 64 + 255) / 256, 256, 0, stream>>>(gw1, p_g1, 2048, 1024);
    pack_w_kernel<<<(64 * 32 * 64 + 255) / 256, 256, 0, stream>>>(aw2, p_a2, 1024, 1024);
    pack_w_kernel<<<(64 * 32 * 64 + 255) / 256, 256, 0, stream>>>(gw2, p_g2, 1024, 1024);
    // Zero barrier slots + recurrent state every call (graph-replay safe).
    hipMemsetAsync(ctrl, 0, 4096 + (size_t)BB * HH * sizeof(unsigned short), stream);

    persist_kernel<<<NWG, NTH, 0, stream>>>(X, p_a1, ab1, p_a2, ab2,
                                            p_g1, gb1, p_g2, gb2,
                                            Out, state, h1, albf, h2,
                                            slots);
}

// Round 11
// 47274.701 us; speedup vs baseline: 1.9511x; 1.5970x over previous
//
#include <hip/hip_runtime.h>
#include <hip/hip_bf16.h>

// Problem constants
#define HH 1024
#define BB 128
#define TT 512
#define NWG 128      // 4 row-groups (mg) x 32 N-slices (ng)
#define NTH 512      // 8 waves: 4 output tiles (2M x 2N) x 2 K-halves
#define NP 32

typedef float        f32x4 __attribute__((ext_vector_type(4)));
typedef short        s16x8 __attribute__((ext_vector_type(8)));

__device__ __forceinline__ unsigned short bf16b(float f) {
    union { __hip_bfloat16 h; unsigned short u; } cv;
    cv.h = __float2bfloat16(f);
    return cv.u;
}

__device__ __forceinline__ float gelu_exact(float x) {
    return 0.5f * x * (1.0f + erff(x * 0.70710678118654752440f));
}

// --- device-coherent (system-scope) accesses for cross-WG producer/consumer.
__device__ __forceinline__ void sc_load_b16x8(s16x8& v, const unsigned short* p) {
    asm volatile("global_load_dwordx4 %0, %1, off sc0 sc1" : "=v"(v) : "v"(p));
}
__device__ __forceinline__ void sc_load_u32(unsigned& v, const unsigned* p) {
    asm volatile("global_load_dword %0, %1, off sc0 sc1" : "=v"(v) : "v"(p));
}
__device__ __forceinline__ void sc_store_b16(unsigned short* p, unsigned int v) {
    asm volatile("global_store_short %0, %1, off sc0 sc1" :: "v"(p), "v"(v) : "memory");
}
__device__ __forceinline__ void sc_store_u32(unsigned* p, unsigned int v) {
    asm volatile("global_store_dword %0, %1, off sc0 sc1" :: "v"(p), "v"(v) : "memory");
}
// --- plain cached load inside the hand-counted asm stream (G1/G3 weights).
__device__ __forceinline__ void pl_load_b16x8(s16x8& v, const unsigned short* p) {
    asm volatile("global_load_dwordx4 %0, %1, off" : "=v"(v) : "v"(p));
}
// --- non-temporal store for streaming Out writes.
__device__ __forceinline__ void nt_store_f32(float* p, float v) {
    asm volatile("global_store_dword %0, %1, off nt" :: "v"(p), "v"(v) : "memory");
}

// ---------------------------------------------------------------------------
// Pack fp32 weight W[K][N] (row-major) into MFMA B-fragment layout, bf16:
//   P[((ntile*KT + ktile)*64 + lane)*8 + j] =
//       bf16(W[ktile*32 + (lane>>4)*8 + j][ntile*16 + (lane&15)])
// ---------------------------------------------------------------------------
__global__ __launch_bounds__(256) void pack_w_kernel(const float* __restrict__ W,
                                                     unsigned short* __restrict__ P,
                                                     int K, int N) {
    int tid = blockIdx.x * 256 + threadIdx.x;
    int KT = K >> 5;
    int total = (N >> 4) * KT * 64;
    if (tid >= total) return;
    int lane  = tid & 63;
    int ktile = (tid >> 6) % KT;
    int ntile = (tid >> 6) / KT;
    int k0 = ktile * 32 + (lane >> 4) * 8;
    int n  = ntile * 16 + (lane & 15);
    unsigned short tmp[8];
#pragma unroll
    for (int j = 0; j < 8; ++j)
        tmp[j] = bf16b(W[(size_t)(k0 + j) * N + n]);
    *reinterpret_cast<s16x8*>(P + (size_t)tid * 8) = *reinterpret_cast<const s16x8*>(tmp);
}

// ---------------------------------------------------------------------------
// Per-GROUP flag barrier (32 WGs / row-group). One slot per 64B line.
// Arrive: drain stores, block sync, one flag store. Wait: wave 0 only polls
// the 32 slots (2 lanes/slot), s_sleep(3) backoff after a miss — r6/r7
// lesson: unthrottled wide polling floods the fabric and slows itself.
// ---------------------------------------------------------------------------
__device__ __forceinline__ void gbar_arrive(unsigned* gs, int ng, unsigned rnd) {
    asm volatile("s_waitcnt vmcnt(0)" ::: "memory");  // drain my sc/nt stores
    __syncthreads();                                   // all 8 waves drained
    if (threadIdx.x == 0)
        sc_store_u32(gs + ng * 16, rnd);
}
__device__ __forceinline__ void gbar_wait(const unsigned* gs, unsigned rnd) {
    if (rnd != 0 && threadIdx.x < 64) {
        const unsigned* p = gs + (threadIdx.x & 31) * 16;
        for (;;) {
            unsigned v;
            sc_load_u32(v, p);
            asm volatile("s_waitcnt vmcnt(0)" ::: "memory");
            if (__all(v >= rnd)) break;
            __builtin_amdgcn_s_sleep(3);   // ~200 clk: caps poll rate
        }
    }
    __syncthreads();
    __builtin_amdgcn_sched_barrier(0);
}

// ---------------------------------------------------------------------------
// G1/G3 state-half K-loop: 2-deep counted-vmcnt pipeline. A (activations) via
// sc loads, B (weights) via plain loads. 8 kt/batch = 16 loads in flight.
// ---------------------------------------------------------------------------
template <int NBLK>
__device__ __forceinline__ f32x4 kloop_pipe(const unsigned short* Abase,
                                            const unsigned short* bp) {
    f32x4 acc = {};
    s16x8 a[2][8], b[2][8];
#pragma unroll
    for (int j = 0; j < 8; ++j)
        sc_load_b16x8(a[0][j], Abase + (size_t)j * 32);
#pragma unroll
    for (int j = 0; j < 8; ++j)
        pl_load_b16x8(b[0][j], bp + (size_t)j * 512);
#pragma unroll
    for (int blk = 0; blk < NBLK; ++blk) {
        const int cur = blk & 1, nxt = cur ^ 1;
        if (blk + 1 < NBLK) {
#pragma unroll
            for (int j = 0; j < 8; ++j)
                sc_load_b16x8(a[nxt][j], Abase + (size_t)((blk + 1) * 8 + j) * 32);
#pragma unroll
            for (int j = 0; j < 8; ++j)
                pl_load_b16x8(b[nxt][j], bp + (size_t)((blk + 1) * 8 + j) * 512);
            asm volatile("s_waitcnt vmcnt(16)" ::: "memory");
        } else {
            asm volatile("s_waitcnt vmcnt(0)" ::: "memory");
        }
        __builtin_amdgcn_sched_barrier(0);
#pragma unroll
        for (int j = 0; j < 8; ++j)
            acc = __builtin_amdgcn_mfma_f32_16x16x32_bf16(a[cur][j], b[cur][j], acc, 0, 0, 0);
    }
    return acc;
}

// ---------------------------------------------------------------------------
// G2/G4 K-half loop: A via sc loads (2-deep, counted vmcnt), B from LDS
// (weights resident on-chip -> zero fetch latency, immune to L2 eviction).
// wl already includes this wave's (gemm, ntile, khalf, lane) offset; B-frag
// for local kt sits at wl + kt*1024 (linear: 2-way bank alias only = free).
// ---------------------------------------------------------------------------
__device__ __forceinline__ f32x4 kloop_ds(const unsigned short* Abase,
                                          const char* wl) {
    f32x4 acc = {};
    s16x8 a[2][8];
#pragma unroll
    for (int j = 0; j < 8; ++j)
        sc_load_b16x8(a[0][j], Abase + (size_t)j * 32);
#pragma unroll
    for (int blk = 0; blk < 2; ++blk) {
        const int cur = blk & 1, nxt = cur ^ 1;
        if (blk == 0) {
#pragma unroll
            for (int j = 0; j < 8; ++j)
                sc_load_b16x8(a[nxt][j], Abase + (size_t)(8 + j) * 32);
            asm volatile("s_waitcnt vmcnt(8)" ::: "memory");
        } else {
            asm volatile("s_waitcnt vmcnt(0)" ::: "memory");
        }
        __builtin_amdgcn_sched_barrier(0);
#pragma unroll
        for (int j = 0; j < 8; ++j) {
            s16x8 b = *reinterpret_cast<const s16x8*>(wl + (size_t)(blk * 8 + j) * 1024);
            acc = __builtin_amdgcn_mfma_f32_16x16x32_bf16(a[cur][j], b, acc, 0, 0, 0);
        }
    }
    return acc;
}

// K-loop over the fp32 input frame: plain cached loads, pure C++ (compiler
// pipelines). Depends only on static X -> run BEFORE the barrier wait.
__device__ __forceinline__ f32x4 kloop_x(const float* xt, const unsigned short* bp) {
    f32x4 acc = {};
#pragma unroll 4
    for (int kt = 0; kt < 32; ++kt) {
        f32x4 lo = *reinterpret_cast<const f32x4*>(xt + kt * 32);
        f32x4 hi = *reinterpret_cast<const f32x4*>(xt + kt * 32 + 4);
        s16x8 a;
#pragma unroll
        for (int j = 0; j < 4; ++j) {
            a[j]     = (short)bf16b(lo[j]);
            a[j + 4] = (short)bf16b(hi[j]);
        }
        s16x8 b = *reinterpret_cast<const s16x8*>(bp + (size_t)kt * 512);
        acc = __builtin_amdgcn_mfma_f32_16x16x32_bf16(a, b, acc, 0, 0, 0);
    }
    return acc;
}

// ---------------------------------------------------------------------------
// Persistent kernel. 4 independent row-groups (mg = wg>>5, 32 rows each),
// each synced among its own 32 WGs (ng = wg&31 -> 32-col slice).
// 8 waves: tile = w&3 (2M x 2N of 16x16), khalf = w>>2 splits K;
// khalf-1 partials reduced into khalf-0 via LDS.
// G2/G4 weights (128 KB: 2 GEMMs x 2 ntiles x 32 kt x 1 KB frags) live in
// LDS, filled once in the prologue. G1/G3 weights plain-cached; X cached;
// activations sc0sc1; Out nt.
// ---------------------------------------------------------------------------
__global__ __launch_bounds__(512, 1) void persist_kernel(
    const float* __restrict__ X,
    const unsigned short* __restrict__ p_a1, const float* __restrict__ ab1,
    const unsigned short* __restrict__ p_a2, const float* __restrict__ ab2,
    const unsigned short* __restrict__ p_g1, const float* __restrict__ gb1,
    const unsigned short* __restrict__ p_g2, const float* __restrict__ gb2,
    float* __restrict__ Out,
    unsigned short* state, unsigned short* h1, unsigned short* albf,
    unsigned short* h2,
    unsigned* slots)
{
    __shared__ __align__(16) char wlds[131072];   // 128 KB G2/G4 weight frags
    __shared__ f32x4 red[4][64];                  // 4 KB split-K reduction

    const int wg    = blockIdx.x;
    const int ng    = wg & (NP - 1);
    const int mg    = wg >> 5;
    const int tid   = threadIdx.x;
    const int lane  = tid & 63;
    const int w     = tid >> 6;       // 0..7
    const int tile  = w & 3;          // 2M x 2N
    const int khalf = w >> 2;         // 0..1
    const int wm    = tile >> 1;
    const int wn    = tile & 1;
    const int r     = lane & 15;
    const int q     = lane >> 4;

    const int mrow  = mg * 32 + wm * 16;
    const int ncol  = ng * 32 + wn * 16;
    const int ntile = ncol >> 4;          // = ng*2 + wn

    unsigned* gs = slots + mg * (NP * 16);   // this group's 32 spread slots

    const size_t arow_off = (size_t)(mrow + r) * HH + q * 8;
    const float* xrow = X + (size_t)(mrow + r) * (TT * HH) + q * 8;

    const unsigned short* bpa1 = p_a1 + ((size_t)ntile * 64) * 512 + (size_t)lane * 8;
    const unsigned short* bpg1 = p_g1 + ((size_t)ntile * 64) * 512 + (size_t)lane * 8;

    const float biasA1 = ab1[ncol + r];
    const float biasA2 = ab2[ncol + r];
    const float biasG1 = gb1[ncol + r];
    const float biasG2 = gb2[ncol + r];

    // ---- prologue: fill LDS with this WG's G2/G4 weight fragments --------
    // wlds linear: idx = g*4096 + ntl*2048 + kt*64 + ln (16B units)
    //   g: 0=aw2, 1=gw2; ntl: 0..1 (= ng*2+ntl global ntile); kt: 0..31.
    for (int idx = tid; idx < 8192; idx += NTH) {
        int g   = idx >> 12;
        int rem = idx & 4095;
        int ntl = rem >> 11;
        int kt  = (rem >> 6) & 31;
        int ln  = rem & 63;
        const unsigned short* src = (g ? p_g2 : p_a2)
            + ((size_t)((ng * 2 + ntl) * 32 + kt) * 64 + ln) * 8;
        *reinterpret_cast<s16x8*>(wlds + (size_t)idx * 16) =
            *reinterpret_cast<const s16x8*>(src);
    }
    __syncthreads();

    // this wave's LDS base for G2 / G4 (includes ntile, khalf, lane):
    const char* wl_a2 = wlds + (size_t)wn * 32768 + (size_t)khalf * 16384
                             + (size_t)lane * 16;
    const char* wl_g2 = wl_a2 + 65536;

    float al_reg[4] = {0.f, 0.f, 0.f, 0.f};   // fp32 'aligned' tile (khalf 0)

    for (int t = 0; t < TT; ++t) {
        const float* xt = xrow + (size_t)t * HH;
        const unsigned rb = 4u * (unsigned)t;

        // ------- G1: h1 = gelu(concat(x_t, state) @ aw1 + ab1), K=2048 -----
        {
            f32x4 acc;
            if (khalf == 0) acc = kloop_x(xt, bpa1);        // x half BEFORE wait
            gbar_wait(gs, rb);                              // state ready
            if (khalf == 1) {
                acc = kloop_pipe<4>(state + arow_off, bpa1 + (size_t)32 * 512);
                red[tile][lane] = acc;
            }
            __syncthreads();
            if (khalf == 0) {
                acc += red[tile][lane];
#pragma unroll
                for (int j = 0; j < 4; ++j) {
                    float v = acc[j] + biasA1;
                    sc_store_b16(h1 + (size_t)(mrow + q * 4 + j) * HH + ncol + r,
                                 bf16b(gelu_exact(v)));
                }
            }
        }
        gbar_arrive(gs, ng, rb + 1);

        // ------- G2: aligned = h1 @ aw2 + ab2, K=1024 (B from LDS) ---------
        {
            gbar_wait(gs, rb + 1);
            f32x4 acc = kloop_ds(h1 + arow_off + (size_t)khalf * 512, wl_a2);
            if (khalf == 1) red[tile][lane] = acc;
            __syncthreads();
            if (khalf == 0) {
                acc += red[tile][lane];
#pragma unroll
                for (int j = 0; j < 4; ++j) {
                    float v = acc[j] + biasA2;
                    al_reg[j] = v;
                    sc_store_b16(albf + (size_t)(mrow + q * 4 + j) * HH + ncol + r,
                                 bf16b(v));
                }
            }
        }
        gbar_arrive(gs, ng, rb + 2);

        // ------- G3: h2 = gelu(concat(x_t, aligned) @ gw1 + gb1), K=2048 ---
        {
            f32x4 acc;
            if (khalf == 0) acc = kloop_x(xt, bpg1);        // x half BEFORE wait
            gbar_wait(gs, rb + 2);                          // albf ready
            if (khalf == 1) {
                acc = kloop_pipe<4>(albf + arow_off, bpg1 + (size_t)32 * 512);
                red[tile][lane] = acc;
            }
            __syncthreads();
            if (khalf == 0) {
                acc += red[tile][lane];
#pragma unroll
                for (int j = 0; j < 4; ++j) {
                    float v = acc[j] + biasG1;
                    sc_store_b16(h2 + (size_t)(mrow + q * 4 + j) * HH + ncol + r,
                                 bf16b(gelu_exact(v)));
                }
            }
        }
        gbar_arrive(gs, ng, rb + 3);

        // ------- G4: gate = sigmoid(h2 @ gw2 + gb2); blend (B from LDS) ----
        {
            gbar_wait(gs, rb + 3);
            f32x4 acc = kloop_ds(h2 + arow_off + (size_t)khalf * 512, wl_g2);
            if (khalf == 1) red[tile][lane] = acc;
            __syncthreads();
            if (khalf == 0) {
                acc += red[tile][lane];
#pragma unroll
                for (int j = 0; j < 4; ++j) {
                    int row = mrow + q * 4 + j;
                    int col = ncol + r;
                    float gl = acc[j] + biasG2;
                    float g  = 1.0f / (1.0f + expf(-gl));
                    float xv = X[(size_t)row * (TT * HH) + (size_t)t * HH + col];
                    float o  = g * al_reg[j] + (1.0f - g) * xv;
                    nt_store_f32(Out + (size_t)row * (TT * HH) + (size_t)t * HH + col, o);
                    sc_store_b16(state + (size_t)row * HH + col, bf16b(o));
                }
            }
        }
        gbar_arrive(gs, ng, rb + 4);
    }
}

extern "C" void kernel_launch(void* const* d_in, const int* in_sizes, int n_in,
                              void* d_out, int out_size, void* d_ws, size_t ws_size,
                              hipStream_t stream) {
    (void)in_sizes; (void)n_in; (void)out_size; (void)ws_size;
    const float* X   = (const float*)d_in[0];
    const float* aw1 = (const float*)d_in[1];
    const float* ab1 = (const float*)d_in[2];
    const float* aw2 = (const float*)d_in[3];
    const float* ab2 = (const float*)d_in[4];
    const float* gw1 = (const float*)d_in[5];
    const float* gb1 = (const float*)d_in[6];
    const float* gw2 = (const float*)d_in[7];
    const float* gb2 = (const float*)d_in[8];
    float* Out = (float*)d_out;

    char* ws = (char*)d_ws;
    unsigned short* p_a1 = (unsigned short*)(ws);                 // 4 MB
    unsigned short* p_g1 = (unsigned short*)(ws + (4u  << 20));   // 4 MB
    unsigned short* p_a2 = (unsigned short*)(ws + (8u  << 20));   // 2 MB
    unsigned short* p_g2 = (unsigned short*)(ws + (10u << 20));   // 2 MB
    char* ctrl = ws + (12u << 20);
    unsigned* slots = (unsigned*)ctrl;                            // 4 grp x 32 slot x 64B = 8 KB
    unsigned short* state = (unsigned short*)(ctrl + 16384);      // 256 KB
    unsigned short* h1    = state + (size_t)BB * HH;              // 256 KB
    unsigned short* albf  = h1    + (size_t)BB * HH;              // 256 KB
    unsigned short* h2    = albf  + (size_t)BB * HH;              // 256 KB

    pack_w_kernel<<<(64 * 64 * 64 + 255) / 256, 256, 0, stream>>>(aw1, p_a1, 2048, 1024);
    pack_w_kernel<<<(64 * 64 * 64 + 255) / 256, 256, 0, stream>>>(gw1, p_g1, 2048, 1024);
    pack_w_kernel<<<(64 * 32 * 64 + 255) / 256, 256, 0, stream>>>(aw2, p_a2, 1024, 1024);
    pack_w_kernel<<<(64 * 32 * 64 + 255) / 256, 256, 0, stream>>>(gw2, p_g2, 1024, 1024);
    // Zero barrier slots + recurrent state every call (graph-replay safe).
    hipMemsetAsync(ctrl, 0, 16384 + (size_t)BB * HH * sizeof(unsigned short), stream);

    persist_kernel<<<NWG, NTH, 0, stream>>>(X, p_a1, ab1, p_a2, ab2,
                                            p_g1, gb1, p_g2, gb2,
                                            Out, state, h1, albf, h2,
                                            slots);
}

// Round 12
// 22949.396 us; speedup vs baseline: 4.0192x; 2.0600x over previous
//
#include <hip/hip_runtime.h>
#include <hip/hip_bf16.h>

// Problem constants
#define HH 1024
#define BB 128
#define TT 512
#define NWG 128      // 32 N-slices (ng = wg>>2, chunk-major) x 4 row-groups (mg = wg&3)
#define NTH 512      // 8 waves: 4 output tiles (2M x 2N) x 2 K-halves
#define NP 32

typedef float        f32x4 __attribute__((ext_vector_type(4)));
typedef short        s16x8 __attribute__((ext_vector_type(8)));
typedef unsigned int u32x2 __attribute__((ext_vector_type(2)));

__device__ __forceinline__ unsigned short bf16b(float f) {
    union { __hip_bfloat16 h; unsigned short u; } cv;
    cv.h = __float2bfloat16(f);
    return cv.u;
}

__device__ __forceinline__ float gelu_exact(float x) {
    return 0.5f * x * (1.0f + erff(x * 0.70710678118654752440f));
}

// --- device-coherent (system-scope) accesses: cross-WG producer/consumer.
__device__ __forceinline__ void sc_load_b16x8(s16x8& v, const unsigned short* p) {
    asm volatile("global_load_dwordx4 %0, %1, off sc0 sc1" : "=v"(v) : "v"(p));
}
__device__ __forceinline__ void sc_load_u32x2(u32x2& v, const unsigned* p) {
    asm volatile("global_load_dwordx2 %0, %1, off sc0 sc1" : "=v"(v) : "v"(p));
}
__device__ __forceinline__ void sc_store_b16(unsigned short* p, unsigned int v) {
    asm volatile("global_store_short %0, %1, off sc0 sc1" :: "v"(p), "v"(v) : "memory");
}
__device__ __forceinline__ void sc_store_u32(unsigned* p, unsigned int v) {
    asm volatile("global_store_dword %0, %1, off sc0 sc1" :: "v"(p), "v"(v) : "memory");
}
// --- plain cached load (weights -> L2-resident if mapping fix works).
__device__ __forceinline__ void pl_load_b16x8(s16x8& v, const unsigned short* p) {
    asm volatile("global_load_dwordx4 %0, %1, off" : "=v"(v) : "v"(p));
}
// --- non-temporal store for streaming Out writes (no L2 pollution).
__device__ __forceinline__ void nt_store_f32(float* p, float v) {
    asm volatile("global_store_dword %0, %1, off nt" :: "v"(p), "v"(v) : "memory");
}
__device__ __forceinline__ void vm_wait0() {
    asm volatile("s_waitcnt vmcnt(0)" ::: "memory");
    __builtin_amdgcn_sched_barrier(0);   // rule #18
}

// ---------------------------------------------------------------------------
// Pack fp32 weight W[K][N] (row-major) into MFMA B-fragment layout, bf16:
//   P[((ntile*KT + ktile)*64 + lane)*8 + j] =
//       bf16(W[ktile*32 + (lane>>4)*8 + j][ntile*16 + (lane&15)])
// ---------------------------------------------------------------------------
__global__ __launch_bounds__(256) void pack_w_kernel(const float* __restrict__ W,
                                                     unsigned short* __restrict__ P,
                                                     int K, int N) {
    int tid = blockIdx.x * 256 + threadIdx.x;
    int KT = K >> 5;
    int total = (N >> 4) * KT * 64;
    if (tid >= total) return;
    int lane  = tid & 63;
    int ktile = (tid >> 6) % KT;
    int ntile = (tid >> 6) / KT;
    int k0 = ktile * 32 + (lane >> 4) * 8;
    int n  = ntile * 16 + (lane & 15);
    unsigned short tmp[8];
#pragma unroll
    for (int j = 0; j < 8; ++j)
        tmp[j] = bf16b(W[(size_t)(k0 + j) * N + n]);
    *reinterpret_cast<s16x8*>(P + (size_t)tid * 8) = *reinterpret_cast<const s16x8*>(tmp);
}

// ---------------------------------------------------------------------------
// r4's PROVEN global flag-array barrier, split arrive/wait (bodies verbatim).
// Arrive: drain stores, block sync, one sc-store of round to own slot.
// Wait: wave 0 polls all 128 slots (2/lane, dwordx2, dense), then block sync.
// ---------------------------------------------------------------------------
__device__ __forceinline__ void gbar_arrive(unsigned* slots, unsigned rnd) {
    asm volatile("s_waitcnt vmcnt(0)" ::: "memory");  // drain my sc/nt stores
    __syncthreads();                                   // all 8 waves drained
    if (threadIdx.x == 0)
        sc_store_u32(slots + blockIdx.x, rnd);
}
__device__ __forceinline__ void gbar_wait(unsigned* slots, unsigned rnd) {
    if (threadIdx.x < 64) {
        const unsigned* p = slots + (threadIdx.x << 1);
        bool done;
        do {
            u32x2 v;
            sc_load_u32x2(v, p);
            asm volatile("s_waitcnt vmcnt(0)" ::: "memory");
            done = __all(v.x >= rnd && v.y >= rnd);
        } while (!done);
    }
    __syncthreads();
    __builtin_amdgcn_sched_barrier(0);
}

// ---------------------------------------------------------------------------
// r4's trickle K-loop (verbatim): A via sc loads, B via plain cached loads,
// 8 kt per batch, vmcnt(0) per batch. bp pre-offset for K-segment.
// ---------------------------------------------------------------------------
template <int NBLK>
__device__ __forceinline__ f32x4 kloop_sc(const unsigned short* Abase,
                                          const unsigned short* bp) {
    f32x4 acc = {};
    for (int blk = 0; blk < NBLK; ++blk) {
        int kb = blk * 8;
        s16x8 a[8], b[8];
#pragma unroll
        for (int j = 0; j < 8; ++j)
            sc_load_b16x8(a[j], Abase + (size_t)(kb + j) * 32);
#pragma unroll
        for (int j = 0; j < 8; ++j)
            b[j] = *reinterpret_cast<const s16x8*>(bp + (size_t)(kb + j) * 512);
        vm_wait0();
#pragma unroll
        for (int j = 0; j < 8; ++j)
            acc = __builtin_amdgcn_mfma_f32_16x16x32_bf16(a[j], b[j], acc, 0, 0, 0);
    }
    return acc;
}

// ---------------------------------------------------------------------------
// G2/G4 K-half loop (r11-proven): A via sc loads (2-deep, counted vmcnt(8)),
// B from LDS-pinned weights. wl includes (gemm, ntile, khalf, lane) offset;
// local kt fragment at wl + kt*1024 (linear, 2-way alias = free).
// ---------------------------------------------------------------------------
__device__ __forceinline__ f32x4 kloop_ds(const unsigned short* Abase,
                                          const char* wl) {
    f32x4 acc = {};
    s16x8 a[2][8];
#pragma unroll
    for (int j = 0; j < 8; ++j)
        sc_load_b16x8(a[0][j], Abase + (size_t)j * 32);
#pragma unroll
    for (int blk = 0; blk < 2; ++blk) {
        const int cur = blk & 1, nxt = cur ^ 1;
        if (blk == 0) {
#pragma unroll
            for (int j = 0; j < 8; ++j)
                sc_load_b16x8(a[nxt][j], Abase + (size_t)(8 + j) * 32);
            asm volatile("s_waitcnt vmcnt(8)" ::: "memory");
        } else {
            asm volatile("s_waitcnt vmcnt(0)" ::: "memory");
        }
        __builtin_amdgcn_sched_barrier(0);
#pragma unroll
        for (int j = 0; j < 8; ++j) {
            s16x8 b = *reinterpret_cast<const s16x8*>(wl + (size_t)(blk * 8 + j) * 1024);
            acc = __builtin_amdgcn_mfma_f32_16x16x32_bf16(a[cur][j], b, acc, 0, 0, 0);
        }
    }
    return acc;
}

// K-loop over the fp32 input frame (r4 verbatim): plain cached loads, pure
// C++. Depends only on static X -> run BEFORE the barrier wait (hoist).
__device__ __forceinline__ f32x4 kloop_x(const float* xt, const unsigned short* bp) {
    f32x4 acc = {};
#pragma unroll 4
    for (int kt = 0; kt < 32; ++kt) {
        f32x4 lo = *reinterpret_cast<const f32x4*>(xt + kt * 32);
        f32x4 hi = *reinterpret_cast<const f32x4*>(xt + kt * 32 + 4);
        s16x8 a;
#pragma unroll
        for (int j = 0; j < 4; ++j) {
            a[j]     = (short)bf16b(lo[j]);
            a[j + 4] = (short)bf16b(hi[j]);
        }
        s16x8 b = *reinterpret_cast<const s16x8*>(bp + (size_t)kt * 512);
        acc = __builtin_amdgcn_mfma_f32_16x16x32_bf16(a, b, acc, 0, 0, 0);
    }
    return acc;
}

// ---------------------------------------------------------------------------
// Persistent kernel (r4 structure). MAPPING: ng = wg>>2 (chunk-major) so
// consecutive blockIdx share one weight slice -> per-XCD weight footprint
// ~1.5 MB under chunked placement (and <=6 MB under round-robin, no worse
// than r4's measured behavior). mg = wg&3.
// 8 waves: tile = w&3 (2M x 2N of 16x16), khalf = w>>2 splits K;
// khalf-1 partials reduced into khalf-0 via 4 KB LDS.
// G2/G4 weights (128 KB) pinned in LDS (r11-proven). G1/G3 weights plain
// cached; X cached; activations sc0sc1; Out nt.
// ---------------------------------------------------------------------------
__global__ __launch_bounds__(512, 1) void persist_kernel(
    const float* __restrict__ X,
    const unsigned short* __restrict__ p_a1, const float* __restrict__ ab1,
    const unsigned short* __restrict__ p_a2, const float* __restrict__ ab2,
    const unsigned short* __restrict__ p_g1, const float* __restrict__ gb1,
    const unsigned short* __restrict__ p_g2, const float* __restrict__ gb2,
    float* __restrict__ Out,
    unsigned short* state, unsigned short* h1, unsigned short* albf,
    unsigned short* h2,
    unsigned* slots)
{
    __shared__ __align__(16) char wlds[131072];   // 128 KB G2/G4 weight frags
    __shared__ f32x4 red[4][64];                  // 4 KB split-K reduction

    const int wg    = blockIdx.x;
    const int ng    = wg >> 2;        // chunk-major N-slice
    const int mg    = wg & 3;         // row-group
    const int tid   = threadIdx.x;
    const int lane  = tid & 63;
    const int w     = tid >> 6;       // 0..7
    const int tile  = w & 3;          // 2M x 2N
    const int khalf = w >> 2;         // 0..1
    const int wm    = tile >> 1;
    const int wn    = tile & 1;
    const int r     = lane & 15;
    const int q     = lane >> 4;

    const int mrow  = mg * 32 + wm * 16;
    const int ncol  = ng * 32 + wn * 16;
    const int ntile = ncol >> 4;          // = ng*2 + wn

    const size_t arow_off = (size_t)(mrow + r) * HH + q * 8;
    const float* xrow = X + (size_t)(mrow + r) * (TT * HH) + q * 8;

    const unsigned short* bpa1 = p_a1 + ((size_t)ntile * 64) * 512 + (size_t)lane * 8;
    const unsigned short* bpg1 = p_g1 + ((size_t)ntile * 64) * 512 + (size_t)lane * 8;

    const float biasA1 = ab1[ncol + r];
    const float biasA2 = ab2[ncol + r];
    const float biasG1 = gb1[ncol + r];
    const float biasG2 = gb2[ncol + r];

    // ---- prologue: pin this WG's G2/G4 weight fragments in LDS -----------
    // byte = g*65536 + ntl*32768 + kt*1024 + ln*16   (g: 0=aw2, 1=gw2)
    for (int idx = tid; idx < 8192; idx += NTH) {
        int g   = idx >> 12;
        int rem = idx & 4095;
        int ntl = rem >> 11;
        int kt  = (rem >> 6) & 31;
        int ln  = rem & 63;
        const unsigned short* src = (g ? p_g2 : p_a2)
            + ((size_t)((ng * 2 + ntl) * 32 + kt) * 64 + ln) * 8;
        *reinterpret_cast<s16x8*>(wlds + (size_t)idx * 16) =
            *reinterpret_cast<const s16x8*>(src);
    }
    __syncthreads();

    // wave's LDS bases (include ntile=wn, khalf, lane):
    const char* wl_a2 = wlds + (size_t)wn * 32768 + (size_t)khalf * 16384
                             + (size_t)lane * 16;
    const char* wl_g2 = wl_a2 + 65536;

    float al_reg[4] = {0.f, 0.f, 0.f, 0.f};   // fp32 'aligned' tile (khalf 0)

    for (int t = 0; t < TT; ++t) {
        const float* xt = xrow + (size_t)t * HH;
        const unsigned rb = 4u * (unsigned)t;

        // ------- G1: h1 = gelu(concat(x_t, state) @ aw1 + ab1), K=2048 -----
        {
            f32x4 acc;
            if (khalf == 0) acc = kloop_x(xt, bpa1);     // x half BEFORE wait
            gbar_wait(slots, rb);                        // state ready (G4 t-1)
            if (khalf == 1) {
                acc = kloop_sc<4>(state + arow_off, bpa1 + (size_t)32 * 512);
                red[tile][lane] = acc;
            }
            __syncthreads();
            if (khalf == 0) {
                acc += red[tile][lane];
#pragma unroll
                for (int j = 0; j < 4; ++j) {
                    float v = acc[j] + biasA1;
                    sc_store_b16(h1 + (size_t)(mrow + q * 4 + j) * HH + ncol + r,
                                 bf16b(gelu_exact(v)));
                }
            }
        }
        gbar_arrive(slots, rb + 1);

        // ------- G2: aligned = h1 @ aw2 + ab2, K=1024 (B from LDS) ---------
        {
            gbar_wait(slots, rb + 1);
            f32x4 acc = kloop_ds(h1 + arow_off + (size_t)khalf * 512, wl_a2);
            if (khalf == 1) red[tile][lane] = acc;
            __syncthreads();
            if (khalf == 0) {
                acc += red[tile][lane];
#pragma unroll
                for (int j = 0; j < 4; ++j) {
                    float v = acc[j] + biasA2;
                    al_reg[j] = v;
                    sc_store_b16(albf + (size_t)(mrow + q * 4 + j) * HH + ncol + r,
                                 bf16b(v));
                }
            }
        }
        gbar_arrive(slots, rb + 2);

        // ------- G3: h2 = gelu(concat(x_t, aligned) @ gw1 + gb1), K=2048 ---
        {
            f32x4 acc;
            if (khalf == 0) acc = kloop_x(xt, bpg1);     // x half BEFORE wait
            gbar_wait(slots, rb + 2);                    // albf ready
            if (khalf == 1) {
                acc = kloop_sc<4>(albf + arow_off, bpg1 + (size_t)32 * 512);
                red[tile][lane] = acc;
            }
            __syncthreads();
            if (khalf == 0) {
                acc += red[tile][lane];
#pragma unroll
                for (int j = 0; j < 4; ++j) {
                    float v = acc[j] + biasG1;
                    sc_store_b16(h2 + (size_t)(mrow + q * 4 + j) * HH + ncol + r,
                                 bf16b(gelu_exact(v)));
                }
            }
        }
        gbar_arrive(slots, rb + 3);

        // ------- G4: gate = sigmoid(h2 @ gw2 + gb2); blend (B from LDS) ----
        {
            gbar_wait(slots, rb + 3);
            f32x4 acc = kloop_ds(h2 + arow_off + (size_t)khalf * 512, wl_g2);
            if (khalf == 1) red[tile][lane] = acc;
            __syncthreads();
            if (khalf == 0) {
                acc += red[tile][lane];
#pragma unroll
                for (int j = 0; j < 4; ++j) {
                    int row = mrow + q * 4 + j;
                    int col = ncol + r;
                    float gl = acc[j] + biasG2;
                    float g  = 1.0f / (1.0f + expf(-gl));
                    float xv = X[(size_t)row * (TT * HH) + (size_t)t * HH + col];
                    float o  = g * al_reg[j] + (1.0f - g) * xv;
                    nt_store_f32(Out + (size_t)row * (TT * HH) + (size_t)t * HH + col, o);
                    sc_store_b16(state + (size_t)row * HH + col, bf16b(o));
                }
            }
        }
        gbar_arrive(slots, rb + 4);
    }
}

extern "C" void kernel_launch(void* const* d_in, const int* in_sizes, int n_in,
                              void* d_out, int out_size, void* d_ws, size_t ws_size,
                              hipStream_t stream) {
    (void)in_sizes; (void)n_in; (void)out_size; (void)ws_size;
    const float* X   = (const float*)d_in[0];
    const float* aw1 = (const float*)d_in[1];
    const float* ab1 = (const float*)d_in[2];
    const float* aw2 = (const float*)d_in[3];
    const float* ab2 = (const float*)d_in[4];
    const float* gw1 = (const float*)d_in[5];
    const float* gb1 = (const float*)d_in[6];
    const float* gw2 = (const float*)d_in[7];
    const float* gb2 = (const float*)d_in[8];
    float* Out = (float*)d_out;

    char* ws = (char*)d_ws;
    unsigned short* p_a1 = (unsigned short*)(ws);                 // 4 MB
    unsigned short* p_g1 = (unsigned short*)(ws + (4u  << 20));   // 4 MB
    unsigned short* p_a2 = (unsigned short*)(ws + (8u  << 20));   // 2 MB
    unsigned short* p_g2 = (unsigned short*)(ws + (10u << 20));   // 2 MB
    char* ctrl = ws + (12u << 20);
    unsigned* slots = (unsigned*)ctrl;                            // 128 u32 (dense, r4)
    unsigned short* state = (unsigned short*)(ctrl + 4096);       // 256 KB
    unsigned short* h1    = state + (size_t)BB * HH;              // 256 KB
    unsigned short* albf  = h1    + (size_t)BB * HH;              // 256 KB
    unsigned short* h2    = albf  + (size_t)BB * HH;              // 256 KB

    pack_w_kernel<<<(64 * 64 * 64 + 255) / 256, 256, 0, stream>>>(aw1, p_a1, 2048, 1024);
    pack_w_kernel<<<(64 * 64 * 64 + 255) / 256, 256, 0, stream>>>(gw1, p_g1, 2048, 1024);
    pack_w_kernel<<<(64 * 32 * 64 + 255) / 256, 256, 0, stream>>>(aw2, p_a2, 1024, 1024);
    pack_w_kernel<<<(64 * 32 * 64 + 255) / 256, 256, 0, stream>>>(gw2, p_g2, 1024, 1024);
    // Zero barrier slots + recurrent state every call (graph-replay safe).
    hipMemsetAsync(ctrl, 0, 4096 + (size_t)BB * HH * sizeof(unsigned short), stream);

    persist_kernel<<<NWG, NTH, 0, stream>>>(X, p_a1, ab1, p_a2, ab2,
                                            p_g1, gb1, p_g2, gb2,
                                            Out, state, h1, albf, h2,
                                            slots);
}

// Round 13
// 21357.875 us; speedup vs baseline: 4.3187x; 1.0745x over previous
//
#include <hip/hip_runtime.h>
#include <hip/hip_bf16.h>

// Problem constants
#define HH 1024
#define BB 128
#define TT 512
#define NWG 128      // 4 row-groups (mg = wg>>5) x 32 N-slices (ng = wg&31, mod-8 XCD-friendly)
#define NTH 512      // 8 waves: 4 output tiles (2M x 2N) x 2 K-halves
#define NP 32

typedef float        f32x4 __attribute__((ext_vector_type(4)));
typedef short        s16x8 __attribute__((ext_vector_type(8)));
typedef unsigned int u32x2 __attribute__((ext_vector_type(2)));

__device__ __forceinline__ unsigned short bf16b(float f) {
    union { __hip_bfloat16 h; unsigned short u; } cv;
    cv.h = __float2bfloat16(f);
    return cv.u;
}

__device__ __forceinline__ float gelu_exact(float x) {
    return 0.5f * x * (1.0f + erff(x * 0.70710678118654752440f));
}

// --- device-coherent (system-scope) accesses: cross-WG producer/consumer.
__device__ __forceinline__ void sc_load_b16x8(s16x8& v, const unsigned short* p) {
    asm volatile("global_load_dwordx4 %0, %1, off sc0 sc1" : "=v"(v) : "v"(p));
}
__device__ __forceinline__ void sc_load_u32x2(u32x2& v, const unsigned* p) {
    asm volatile("global_load_dwordx2 %0, %1, off sc0 sc1" : "=v"(v) : "v"(p));
}
__device__ __forceinline__ void sc_store_b16(unsigned short* p, unsigned int v) {
    asm volatile("global_store_short %0, %1, off sc0 sc1" :: "v"(p), "v"(v) : "memory");
}
__device__ __forceinline__ void sc_store_u32(unsigned* p, unsigned int v) {
    asm volatile("global_store_dword %0, %1, off sc0 sc1" :: "v"(p), "v"(v) : "memory");
}
// --- plain cached load (weights -> L2-resident under mod-8 mapping).
__device__ __forceinline__ void pl_load_b16x8(s16x8& v, const unsigned short* p) {
    asm volatile("global_load_dwordx4 %0, %1, off" : "=v"(v) : "v"(p));
}
// --- non-temporal store for streaming Out writes (no L2 pollution).
__device__ __forceinline__ void nt_store_f32(float* p, float v) {
    asm volatile("global_store_dword %0, %1, off nt" :: "v"(p), "v"(v) : "memory");
}
__device__ __forceinline__ void vm_wait0() {
    asm volatile("s_waitcnt vmcnt(0)" ::: "memory");
    __builtin_amdgcn_sched_barrier(0);   // rule #18
}

// ---------------------------------------------------------------------------
// Pack fp32 weight W[K][N] (row-major) into MFMA B-fragment layout, bf16.
// ---------------------------------------------------------------------------
__global__ __launch_bounds__(256) void pack_w_kernel(const float* __restrict__ W,
                                                     unsigned short* __restrict__ P,
                                                     int K, int N) {
    int tid = blockIdx.x * 256 + threadIdx.x;
    int KT = K >> 5;
    int total = (N >> 4) * KT * 64;
    if (tid >= total) return;
    int lane  = tid & 63;
    int ktile = (tid >> 6) % KT;
    int ntile = (tid >> 6) / KT;
    int k0 = ktile * 32 + (lane >> 4) * 8;
    int n  = ntile * 16 + (lane & 15);
    unsigned short tmp[8];
#pragma unroll
    for (int j = 0; j < 8; ++j)
        tmp[j] = bf16b(W[(size_t)(k0 + j) * N + n]);
    *reinterpret_cast<s16x8*>(P + (size_t)tid * 8) = *reinterpret_cast<const s16x8*>(tmp);
}

// ---------------------------------------------------------------------------
// Pack fp32 X into bf16 (identical rounding to the on-the-fly path).
// ---------------------------------------------------------------------------
__global__ __launch_bounds__(256) void pack_x_kernel(const float* __restrict__ X,
                                                     unsigned short* __restrict__ Xb,
                                                     int n8) {
    int i = blockIdx.x * 256 + threadIdx.x;
    if (i >= n8) return;
    f32x4 lo = *reinterpret_cast<const f32x4*>(X + (size_t)i * 8);
    f32x4 hi = *reinterpret_cast<const f32x4*>(X + (size_t)i * 8 + 4);
    unsigned short tmp[8];
#pragma unroll
    for (int j = 0; j < 4; ++j) {
        tmp[j]     = bf16b(lo[j]);
        tmp[j + 4] = bf16b(hi[j]);
    }
    *reinterpret_cast<s16x8*>(Xb + (size_t)i * 8) = *reinterpret_cast<const s16x8*>(tmp);
}

// ---------------------------------------------------------------------------
// r4's PROVEN global flag-array barrier (bodies verbatim).
// ---------------------------------------------------------------------------
__device__ __forceinline__ void gbar_arrive(unsigned* slots, unsigned rnd) {
    asm volatile("s_waitcnt vmcnt(0)" ::: "memory");  // drain my sc/nt stores
    __syncthreads();                                   // all 8 waves drained
    if (threadIdx.x == 0)
        sc_store_u32(slots + blockIdx.x, rnd);
}
__device__ __forceinline__ void gbar_wait(unsigned* slots, unsigned rnd) {
    if (threadIdx.x < 64) {
        const unsigned* p = slots + (threadIdx.x << 1);
        bool done;
        do {
            u32x2 v;
            sc_load_u32x2(v, p);
            asm volatile("s_waitcnt vmcnt(0)" ::: "memory");
            done = __all(v.x >= rnd && v.y >= rnd);
        } while (!done);
    }
    __syncthreads();
    __builtin_amdgcn_sched_barrier(0);
}

// ---------------------------------------------------------------------------
// r4's trickle K-loop (verbatim): A via sc loads, B via plain cached loads,
// 8 kt per batch, vmcnt(0) per batch. bp pre-offset for K-segment.
// ---------------------------------------------------------------------------
template <int NBLK>
__device__ __forceinline__ f32x4 kloop_sc(const unsigned short* Abase,
                                          const unsigned short* bp) {
    f32x4 acc = {};
    for (int blk = 0; blk < NBLK; ++blk) {
        int kb = blk * 8;
        s16x8 a[8], b[8];
#pragma unroll
        for (int j = 0; j < 8; ++j)
            sc_load_b16x8(a[j], Abase + (size_t)(kb + j) * 32);
#pragma unroll
        for (int j = 0; j < 8; ++j)
            b[j] = *reinterpret_cast<const s16x8*>(bp + (size_t)(kb + j) * 512);
        vm_wait0();
#pragma unroll
        for (int j = 0; j < 8; ++j)
            acc = __builtin_amdgcn_mfma_f32_16x16x32_bf16(a[j], b[j], acc, 0, 0, 0);
    }
    return acc;
}

// ---------------------------------------------------------------------------
// G2/G4 K-half loop (r11/r12-proven): A via sc loads (2-deep counted vmcnt),
// B from LDS-pinned weights.
// ---------------------------------------------------------------------------
__device__ __forceinline__ f32x4 kloop_ds(const unsigned short* Abase,
                                          const char* wl) {
    f32x4 acc = {};
    s16x8 a[2][8];
#pragma unroll
    for (int j = 0; j < 8; ++j)
        sc_load_b16x8(a[0][j], Abase + (size_t)j * 32);
#pragma unroll
    for (int blk = 0; blk < 2; ++blk) {
        const int cur = blk & 1, nxt = cur ^ 1;
        if (blk == 0) {
#pragma unroll
            for (int j = 0; j < 8; ++j)
                sc_load_b16x8(a[nxt][j], Abase + (size_t)(8 + j) * 32);
            asm volatile("s_waitcnt vmcnt(8)" ::: "memory");
        } else {
            asm volatile("s_waitcnt vmcnt(0)" ::: "memory");
        }
        __builtin_amdgcn_sched_barrier(0);
#pragma unroll
        for (int j = 0; j < 8; ++j) {
            s16x8 b = *reinterpret_cast<const s16x8*>(wl + (size_t)(blk * 8 + j) * 1024);
            acc = __builtin_amdgcn_mfma_f32_16x16x32_bf16(a[cur][j], b, acc, 0, 0, 0);
        }
    }
    return acc;
}

// x-half K-loops (run BEFORE the barrier wait). XBF=true: bf16 pre-packed X
// (pure 16B loads). XBF=false: fp32 X with on-the-fly convert (r4 verbatim).
__device__ __forceinline__ f32x4 kloop_xb(const unsigned short* xtb,
                                          const unsigned short* bp) {
    f32x4 acc = {};
#pragma unroll 8
    for (int kt = 0; kt < 32; ++kt) {
        s16x8 a = *reinterpret_cast<const s16x8*>(xtb + kt * 32);
        s16x8 b = *reinterpret_cast<const s16x8*>(bp + (size_t)kt * 512);
        acc = __builtin_amdgcn_mfma_f32_16x16x32_bf16(a, b, acc, 0, 0, 0);
    }
    return acc;
}
__device__ __forceinline__ f32x4 kloop_xf(const float* xt, const unsigned short* bp) {
    f32x4 acc = {};
#pragma unroll 4
    for (int kt = 0; kt < 32; ++kt) {
        f32x4 lo = *reinterpret_cast<const f32x4*>(xt + kt * 32);
        f32x4 hi = *reinterpret_cast<const f32x4*>(xt + kt * 32 + 4);
        s16x8 a;
#pragma unroll
        for (int j = 0; j < 4; ++j) {
            a[j]     = (short)bf16b(lo[j]);
            a[j + 4] = (short)bf16b(hi[j]);
        }
        s16x8 b = *reinterpret_cast<const s16x8*>(bp + (size_t)kt * 512);
        acc = __builtin_amdgcn_mfma_f32_16x16x32_bf16(a, b, acc, 0, 0, 0);
    }
    return acc;
}

// ---------------------------------------------------------------------------
// Persistent kernel (r12 structure). MAPPING: ng = wg&31 (mod-8 XCD-friendly:
// under round-robin placement each XCD sees only 4 ng slices -> 1 MB of G1/G3
// weights, L2-resident). G2/G4 weights (128 KB) pinned in LDS. x-half hoisted
// before the barrier wait. Activations sc0sc1; Out nt; X bf16-prepacked.
// ---------------------------------------------------------------------------
template <bool XBF>
__global__ __launch_bounds__(512, 1) void persist_kernel(
    const float* __restrict__ X, const unsigned short* __restrict__ Xb,
    const unsigned short* __restrict__ p_a1, const float* __restrict__ ab1,
    const unsigned short* __restrict__ p_a2, const float* __restrict__ ab2,
    const unsigned short* __restrict__ p_g1, const float* __restrict__ gb1,
    const unsigned short* __restrict__ p_g2, const float* __restrict__ gb2,
    float* __restrict__ Out,
    unsigned short* state, unsigned short* h1, unsigned short* albf,
    unsigned short* h2,
    unsigned* slots)
{
    __shared__ __align__(16) char wlds[131072];   // 128 KB G2/G4 weight frags
    __shared__ f32x4 red[4][64];                  // 4 KB split-K reduction

    const int wg    = blockIdx.x;
    const int ng    = wg & (NP - 1);  // mod-8 XCD-friendly N-slice
    const int mg    = wg >> 5;        // row-group
    const int tid   = threadIdx.x;
    const int lane  = tid & 63;
    const int w     = tid >> 6;       // 0..7
    const int tile  = w & 3;          // 2M x 2N
    const int khalf = w >> 2;         // 0..1
    const int wm    = tile >> 1;
    const int wn    = tile & 1;
    const int r     = lane & 15;
    const int q     = lane >> 4;

    const int mrow  = mg * 32 + wm * 16;
    const int ncol  = ng * 32 + wn * 16;
    const int ntile = ncol >> 4;          // = ng*2 + wn

    const size_t arow_off = (size_t)(mrow + r) * HH + q * 8;
    const float*          xrow  = X  + (size_t)(mrow + r) * (TT * HH) + q * 8;
    const unsigned short* xrowb = Xb + (size_t)(mrow + r) * (TT * HH) + q * 8;

    const unsigned short* bpa1 = p_a1 + ((size_t)ntile * 64) * 512 + (size_t)lane * 8;
    const unsigned short* bpg1 = p_g1 + ((size_t)ntile * 64) * 512 + (size_t)lane * 8;

    const float biasA1 = ab1[ncol + r];
    const float biasA2 = ab2[ncol + r];
    const float biasG1 = gb1[ncol + r];
    const float biasG2 = gb2[ncol + r];

    // ---- prologue: pin this WG's G2/G4 weight fragments in LDS -----------
    for (int idx = tid; idx < 8192; idx += NTH) {
        int g   = idx >> 12;
        int rem = idx & 4095;
        int ntl = rem >> 11;
        int kt  = (rem >> 6) & 31;
        int ln  = rem & 63;
        const unsigned short* src = (g ? p_g2 : p_a2)
            + ((size_t)((ng * 2 + ntl) * 32 + kt) * 64 + ln) * 8;
        *reinterpret_cast<s16x8*>(wlds + (size_t)idx * 16) =
            *reinterpret_cast<const s16x8*>(src);
    }
    __syncthreads();

    const char* wl_a2 = wlds + (size_t)wn * 32768 + (size_t)khalf * 16384
                             + (size_t)lane * 16;
    const char* wl_g2 = wl_a2 + 65536;

    float al_reg[4] = {0.f, 0.f, 0.f, 0.f};   // fp32 'aligned' tile (khalf 0)

    for (int t = 0; t < TT; ++t) {
        const float*          xt  = xrow  + (size_t)t * HH;
        const unsigned short* xtb = xrowb + (size_t)t * HH;
        const unsigned rb = 4u * (unsigned)t;

        // ------- G1: h1 = gelu(concat(x_t, state) @ aw1 + ab1), K=2048 -----
        {
            f32x4 acc;
            if (khalf == 0)                              // x half BEFORE wait
                acc = XBF ? kloop_xb(xtb, bpa1) : kloop_xf(xt, bpa1);
            gbar_wait(slots, rb);                        // state ready (G4 t-1)
            if (khalf == 1) {
                acc = kloop_sc<4>(state + arow_off, bpa1 + (size_t)32 * 512);
                red[tile][lane] = acc;
            }
            __syncthreads();
            if (khalf == 0) {
                acc += red[tile][lane];
#pragma unroll
                for (int j = 0; j < 4; ++j) {
                    float v = acc[j] + biasA1;
                    sc_store_b16(h1 + (size_t)(mrow + q * 4 + j) * HH + ncol + r,
                                 bf16b(gelu_exact(v)));
                }
            }
        }
        gbar_arrive(slots, rb + 1);

        // ------- G2: aligned = h1 @ aw2 + ab2, K=1024 (B from LDS) ---------
        {
            gbar_wait(slots, rb + 1);
            f32x4 acc = kloop_ds(h1 + arow_off + (size_t)khalf * 512, wl_a2);
            if (khalf == 1) red[tile][lane] = acc;
            __syncthreads();
            if (khalf == 0) {
                acc += red[tile][lane];
#pragma unroll
                for (int j = 0; j < 4; ++j) {
                    float v = acc[j] + biasA2;
                    al_reg[j] = v;
                    sc_store_b16(albf + (size_t)(mrow + q * 4 + j) * HH + ncol + r,
                                 bf16b(v));
                }
            }
        }
        gbar_arrive(slots, rb + 2);

        // ------- G3: h2 = gelu(concat(x_t, aligned) @ gw1 + gb1), K=2048 ---
        {
            f32x4 acc;
            if (khalf == 0)                              // x half BEFORE wait
                acc = XBF ? kloop_xb(xtb, bpg1) : kloop_xf(xt, bpg1);
            gbar_wait(slots, rb + 2);                    // albf ready
            if (khalf == 1) {
                acc = kloop_sc<4>(albf + arow_off, bpg1 + (size_t)32 * 512);
                red[tile][lane] = acc;
            }
            __syncthreads();
            if (khalf == 0) {
                acc += red[tile][lane];
#pragma unroll
                for (int j = 0; j < 4; ++j) {
                    float v = acc[j] + biasG1;
                    sc_store_b16(h2 + (size_t)(mrow + q * 4 + j) * HH + ncol + r,
                                 bf16b(gelu_exact(v)));
                }
            }
        }
        gbar_arrive(slots, rb + 3);

        // ------- G4: gate = sigmoid(h2 @ gw2 + gb2); blend (B from LDS) ----
        {
            gbar_wait(slots, rb + 3);
            f32x4 acc = kloop_ds(h2 + arow_off + (size_t)khalf * 512, wl_g2);
            if (khalf == 1) red[tile][lane] = acc;
            __syncthreads();
            if (khalf == 0) {
                acc += red[tile][lane];
#pragma unroll
                for (int j = 0; j < 4; ++j) {
                    int row = mrow + q * 4 + j;
                    int col = ncol + r;
                    float gl = acc[j] + biasG2;
                    float g  = 1.0f / (1.0f + expf(-gl));
                    float xv = X[(size_t)row * (TT * HH) + (size_t)t * HH + col];
                    float o  = g * al_reg[j] + (1.0f - g) * xv;
                    nt_store_f32(Out + (size_t)row * (TT * HH) + (size_t)t * HH + col, o);
                    sc_store_b16(state + (size_t)row * HH + col, bf16b(o));
                }
            }
        }
        gbar_arrive(slots, rb + 4);
    }
}

extern "C" void kernel_launch(void* const* d_in, const int* in_sizes, int n_in,
                              void* d_out, int out_size, void* d_ws, size_t ws_size,
                              hipStream_t stream) {
    (void)in_sizes; (void)n_in; (void)out_size;
    const float* X   = (const float*)d_in[0];
    const float* aw1 = (const float*)d_in[1];
    const float* ab1 = (const float*)d_in[2];
    const float* aw2 = (const float*)d_in[3];
    const float* ab2 = (const float*)d_in[4];
    const float* gw1 = (const float*)d_in[5];
    const float* gb1 = (const float*)d_in[6];
    const float* gw2 = (const float*)d_in[7];
    const float* gb2 = (const float*)d_in[8];
    float* Out = (float*)d_out;

    char* ws = (char*)d_ws;
    unsigned short* p_a1 = (unsigned short*)(ws);                 // 4 MB
    unsigned short* p_g1 = (unsigned short*)(ws + (4u  << 20));   // 4 MB
    unsigned short* p_a2 = (unsigned short*)(ws + (8u  << 20));   // 2 MB
    unsigned short* p_g2 = (unsigned short*)(ws + (10u << 20));   // 2 MB
    char* ctrl = ws + (12u << 20);
    unsigned* slots = (unsigned*)ctrl;                            // 128 u32 (dense, r4)
    unsigned short* state = (unsigned short*)(ctrl + 4096);       // 256 KB
    unsigned short* h1    = state + (size_t)BB * HH;              // 256 KB
    unsigned short* albf  = h1    + (size_t)BB * HH;              // 256 KB
    unsigned short* h2    = albf  + (size_t)BB * HH;              // 256 KB
    unsigned short* xbf   = (unsigned short*)(ws + (16u << 20));  // 128 MB (optional)

    const size_t xbf_need = (16u << 20) + (size_t)BB * TT * HH * sizeof(unsigned short);
    const bool use_xbf = (ws_size >= xbf_need);

    pack_w_kernel<<<(64 * 64 * 64 + 255) / 256, 256, 0, stream>>>(aw1, p_a1, 2048, 1024);
    pack_w_kernel<<<(64 * 64 * 64 + 255) / 256, 256, 0, stream>>>(gw1, p_g1, 2048, 1024);
    pack_w_kernel<<<(64 * 32 * 64 + 255) / 256, 256, 0, stream>>>(aw2, p_a2, 1024, 1024);
    pack_w_kernel<<<(64 * 32 * 64 + 255) / 256, 256, 0, stream>>>(gw2, p_g2, 1024, 1024);
    if (use_xbf) {
        int n8 = BB * TT * HH / 8;
        pack_x_kernel<<<(n8 + 255) / 256, 256, 0, stream>>>(X, xbf, n8);
    }
    // Zero barrier slots + recurrent state every call (graph-replay safe).
    hipMemsetAsync(ctrl, 0, 4096 + (size_t)BB * HH * sizeof(unsigned short), stream);

    if (use_xbf)
        persist_kernel<true><<<NWG, NTH, 0, stream>>>(X, xbf, p_a1, ab1, p_a2, ab2,
                                                      p_g1, gb1, p_g2, gb2,
                                                      Out, state, h1, albf, h2, slots);
    else
        persist_kernel<false><<<NWG, NTH, 0, stream>>>(X, xbf, p_a1, ab1, p_a2, ab2,
                                                       p_g1, gb1, p_g2, gb2,
                                                       Out, state, h1, albf, h2, slots);
}